// Round 10
// baseline (170.271 us; speedup 1.0000x reference)
//
#include <hip/hip_runtime.h>
#include <stdint.h>

// q,k,v: [B=8, d=768, N=6144] fp32; head_dim=32, kernel_size=3
// h=24 heads, g=2048 windows; window elem j of window gg at n = j*2048 + gg
// out flat: [b][gg][hh][kq][dd] contiguous [8, 2048, 24, 3, 32]
//
// Round 10: continuous-issue pipeline. Rounds 4-9 falsified occupancy
// (27->77% flat) and spatial pattern (64B islands vs 1KB bursts flat) as
// limiters; combined service is 4.7 of ~6.3 TB/s. Remaining delta vs the
// copy ubench: duty cycle of load issue (burst-wait-burst vs continuous).
//  - r8 compute structure: 4 threads/window (slice owns dd-octet), partial
//    scores combined via shfl_xor(16/32), softmax redundant per slice,
//    PV register-only, full-line stores (measured amp-free).
//  - Persistent waves: each wave walks 8 consecutive window-groups.
//    Body i: issue v[i] loads -> issue qk[i+1] prefetch (ping-pong regs)
//    -> scores/shfl/softmax of body i (VALU under ~72 flying loads)
//    -> PV waits vmcnt(48): v[i] drained, qk[i+1] stays in flight.
//  - Fully unrolled; it&1 ping-pong indices are compile-time (no scratch).
//  - ~155 VGPR -> 2 waves/SIMD; ILP supplies queue fill instead of TLP
//    (proven equivalent across r4-r8). NO launch_bounds min-waves.
constexpr int CB = 8;
constexpr int CD = 768;
constexpr int CN = 6144;
constexpr int HD = 32;
constexpr int KS = 3;
constexpr int CH = CD / HD;        // 24
constexpr int CG = CN / KS;        // 2048
constexpr int OSTR = CH * KS * HD; // 2304
constexpr int ITER = 8;            // window-groups per wave

__global__ __launch_bounds__(256) void dilate_attn_kernel(
    const float* __restrict__ q, const float* __restrict__ k,
    const float* __restrict__ v, float* __restrict__ out) {
  const int tid   = blockIdx.x * 256 + threadIdx.x;
  const int lane  = threadIdx.x & 63;
  const int wv    = tid >> 6;        // 0..3071
  const int slice = lane >> 4;       // dd-octet owner
  const int wl    = lane & 15;       // window within group
  const int bh    = wv >> 4;         // b*24 + hh
  const int hh    = bh % CH;
  const int b     = bh / CH;
  const int gg0   = (wv & 15) * 128 + wl;  // advances +16 per body

  uint32_t inoff = (uint32_t)(b * CD + hh * HD + slice * 8) * (uint32_t)CN
                 + (uint32_t)gg0;
  uint32_t ooff  = (uint32_t)(b * CG + gg0) * (uint32_t)OSTR
                 + (uint32_t)(hh * KS * HD + slice * 8);

  float qr[2][24], kr[2][24];

  // preload body 0's q,k
  #pragma unroll
  for (int d = 0; d < 8; ++d) {
    const uint32_t o = inoff + (uint32_t)d * CN;
    qr[0][d] = q[o]; qr[0][8 + d] = q[o + CG]; qr[0][16 + d] = q[o + 2 * CG];
    kr[0][d] = k[o]; kr[0][8 + d] = k[o + CG]; kr[0][16 + d] = k[o + 2 * CG];
  }

  #pragma unroll
  for (int it = 0; it < ITER; ++it) {
    const int cur = it & 1, nxt = cur ^ 1;

    // ---- v loads for this body (first in program order: PV's wait leaves
    // the qk prefetch below in flight)
    float va[8], vb2[8], vc2[8];
    #pragma unroll
    for (int d = 0; d < 8; ++d) {
      const uint32_t o = inoff + (uint32_t)d * CN;
      va[d] = v[o]; vb2[d] = v[o + CG]; vc2[d] = v[o + 2 * CG];
    }

    // ---- prefetch next body's q,k into the other buffer
    if (it + 1 < ITER) {
      const uint32_t o1 = inoff + 16;
      #pragma unroll
      for (int d = 0; d < 8; ++d) {
        const uint32_t o = o1 + (uint32_t)d * CN;
        qr[nxt][d] = q[o]; qr[nxt][8 + d] = q[o + CG]; qr[nxt][16 + d] = q[o + 2 * CG];
        kr[nxt][d] = k[o]; kr[nxt][8 + d] = k[o + CG]; kr[nxt][16 + d] = k[o + 2 * CG];
      }
    }

    // ---- partial scores from this body's registers
    float s00 = 0.f, s01 = 0.f, s02 = 0.f;
    float s10 = 0.f, s11 = 0.f, s12 = 0.f;
    float s20 = 0.f, s21 = 0.f, s22 = 0.f;
    #pragma unroll
    for (int d = 0; d < 8; ++d) {
      const float q0 = qr[cur][d], q1 = qr[cur][8 + d], q2 = qr[cur][16 + d];
      const float k0 = kr[cur][d], k1 = kr[cur][8 + d], k2 = kr[cur][16 + d];
      s00 = fmaf(q0, k0, s00); s01 = fmaf(q0, k1, s01); s02 = fmaf(q0, k2, s02);
      s10 = fmaf(q1, k0, s10); s11 = fmaf(q1, k1, s11); s12 = fmaf(q1, k2, s12);
      s20 = fmaf(q2, k0, s20); s21 = fmaf(q2, k1, s21); s22 = fmaf(q2, k2, s22);
    }

    // ---- combine across the 4 slices (lane^16, lane^32)
    s00 += __shfl_xor(s00, 16); s01 += __shfl_xor(s01, 16); s02 += __shfl_xor(s02, 16);
    s10 += __shfl_xor(s10, 16); s11 += __shfl_xor(s11, 16); s12 += __shfl_xor(s12, 16);
    s20 += __shfl_xor(s20, 16); s21 += __shfl_xor(s21, 16); s22 += __shfl_xor(s22, 16);
    s00 += __shfl_xor(s00, 32); s01 += __shfl_xor(s01, 32); s02 += __shfl_xor(s02, 32);
    s10 += __shfl_xor(s10, 32); s11 += __shfl_xor(s11, 32); s12 += __shfl_xor(s12, 32);
    s20 += __shfl_xor(s20, 32); s21 += __shfl_xor(s21, 32); s22 += __shfl_xor(s22, 32);

    // ---- softmax over kj, in place (redundant in all 4 slices)
    const float scale = 0.17677669529663687f;  // 32^-0.5
    {
      const float x0 = s00 * scale, x1 = s01 * scale, x2 = s02 * scale;
      const float m = fmaxf(fmaxf(x0, x1), x2);
      const float e0 = __expf(x0 - m), e1 = __expf(x1 - m), e2 = __expf(x2 - m);
      const float r = 1.f / (e0 + e1 + e2);
      s00 = e0 * r; s01 = e1 * r; s02 = e2 * r;
    }
    {
      const float x0 = s10 * scale, x1 = s11 * scale, x2 = s12 * scale;
      const float m = fmaxf(fmaxf(x0, x1), x2);
      const float e0 = __expf(x0 - m), e1 = __expf(x1 - m), e2 = __expf(x2 - m);
      const float r = 1.f / (e0 + e1 + e2);
      s10 = e0 * r; s11 = e1 * r; s12 = e2 * r;
    }
    {
      const float x0 = s20 * scale, x1 = s21 * scale, x2 = s22 * scale;
      const float m = fmaxf(fmaxf(x0, x1), x2);
      const float e0 = __expf(x0 - m), e1 = __expf(x1 - m), e2 = __expf(x2 - m);
      const float r = 1.f / (e0 + e1 + e2);
      s20 = e0 * r; s21 = e1 * r; s22 = e2 * r;
    }

    // ---- PV from v registers (waits vmcnt on v only), immediate stores
    float o0, o1, o2, o3, o4, o5, o6, o7;
    o0 = fmaf(s00, va[0], fmaf(s01, vb2[0], s02 * vc2[0]));
    o1 = fmaf(s00, va[1], fmaf(s01, vb2[1], s02 * vc2[1]));
    o2 = fmaf(s00, va[2], fmaf(s01, vb2[2], s02 * vc2[2]));
    o3 = fmaf(s00, va[3], fmaf(s01, vb2[3], s02 * vc2[3]));
    o4 = fmaf(s00, va[4], fmaf(s01, vb2[4], s02 * vc2[4]));
    o5 = fmaf(s00, va[5], fmaf(s01, vb2[5], s02 * vc2[5]));
    o6 = fmaf(s00, va[6], fmaf(s01, vb2[6], s02 * vc2[6]));
    o7 = fmaf(s00, va[7], fmaf(s01, vb2[7], s02 * vc2[7]));
    *reinterpret_cast<float4*>(out + ooff + 0 * HD)     = make_float4(o0, o1, o2, o3);
    *reinterpret_cast<float4*>(out + ooff + 0 * HD + 4) = make_float4(o4, o5, o6, o7);

    o0 = fmaf(s10, va[0], fmaf(s11, vb2[0], s12 * vc2[0]));
    o1 = fmaf(s10, va[1], fmaf(s11, vb2[1], s12 * vc2[1]));
    o2 = fmaf(s10, va[2], fmaf(s11, vb2[2], s12 * vc2[2]));
    o3 = fmaf(s10, va[3], fmaf(s11, vb2[3], s12 * vc2[3]));
    o4 = fmaf(s10, va[4], fmaf(s11, vb2[4], s12 * vc2[4]));
    o5 = fmaf(s10, va[5], fmaf(s11, vb2[5], s12 * vc2[5]));
    o6 = fmaf(s10, va[6], fmaf(s11, vb2[6], s12 * vc2[6]));
    o7 = fmaf(s10, va[7], fmaf(s11, vb2[7], s12 * vc2[7]));
    *reinterpret_cast<float4*>(out + ooff + 1 * HD)     = make_float4(o0, o1, o2, o3);
    *reinterpret_cast<float4*>(out + ooff + 1 * HD + 4) = make_float4(o4, o5, o6, o7);

    o0 = fmaf(s20, va[0], fmaf(s21, vb2[0], s22 * vc2[0]));
    o1 = fmaf(s20, va[1], fmaf(s21, vb2[1], s22 * vc2[1]));
    o2 = fmaf(s20, va[2], fmaf(s21, vb2[2], s22 * vc2[2]));
    o3 = fmaf(s20, va[3], fmaf(s21, vb2[3], s22 * vc2[3]));
    o4 = fmaf(s20, va[4], fmaf(s21, vb2[4], s22 * vc2[4]));
    o5 = fmaf(s20, va[5], fmaf(s21, vb2[5], s22 * vc2[5]));
    o6 = fmaf(s20, va[6], fmaf(s21, vb2[6], s22 * vc2[6]));
    o7 = fmaf(s20, va[7], fmaf(s21, vb2[7], s22 * vc2[7]));
    *reinterpret_cast<float4*>(out + ooff + 2 * HD)     = make_float4(o0, o1, o2, o3);
    *reinterpret_cast<float4*>(out + ooff + 2 * HD + 4) = make_float4(o4, o5, o6, o7);

    inoff += 16u;
    ooff  += 16u * OSTR;  // 16 windows forward
  }
}

extern "C" void kernel_launch(void* const* d_in, const int* in_sizes, int n_in,
                              void* d_out, int out_size, void* d_ws, size_t ws_size,
                              hipStream_t stream) {
  const float* q = (const float*)d_in[0];
  const float* k = (const float*)d_in[1];
  const float* v = (const float*)d_in[2];
  float* out = (float*)d_out;

  // 3072 persistent waves (x8 bodies = 24576 wave-groups) = 768 blocks (3/CU)
  const int blocks = 768;
  dilate_attn_kernel<<<blocks, 256, 0, stream>>>(q, k, v, out);
}

// Round 11
// 118.547 us; speedup vs baseline: 1.4363x; 1.4363x over previous
//
#include <hip/hip_runtime.h>
#include <stdint.h>

// q,k,v: [B=8, d=768, N=6144] fp32; head_dim=32, kernel_size=3
// h=24 heads, g=2048 windows; window elem j of window gg at n = j*2048 + gg
// out flat: [b][gg][hh][kq][dd] contiguous [8, 2048, 24, 3, 32]
//
// Round 11: double bytes-per-outstanding-request. Evidence r4-r10: BW flat
// vs occupancy (27-77%) and vs burst contiguity, but RISES with per-wave
// in-flight bytes (r10's accidental 2x load count -> 3.6 TB/s at 27% occ).
// Hypothesis: bounded outstanding-request slots; scalar loads carry only
// 256B/slot. Fix: 2 windows per thread, ALL loads float2 (512B/instr),
// keeping r8's proven skeleton:
//  - 4 threads per window (slice owns dd-octet), partial scores combined
//    via shfl_xor(16/32); softmax redundant per slice, in-place.
//  - v preloaded (24 float2 = 48 VGPR) before shuffle+softmax VALU phase.
//  - stores: full 64B lines back-to-back per (window,kq) -- measured
//    amp-free (WRITE=148MB) in r5/r8.
//  - s[a][c] are float2 (.x=win gg, .y=win gg+1): 18 accumulator VGPRs.
//  - ~90-100 VGPR target, NO launch_bounds min-waves (r6 spill lesson).
constexpr int CB = 8;
constexpr int CD = 768;
constexpr int CN = 6144;
constexpr int HD = 32;
constexpr int KS = 3;
constexpr int CH = CD / HD;        // 24
constexpr int CG = CN / KS;        // 2048
constexpr int OSTR = CH * KS * HD; // 2304

__global__ __launch_bounds__(256) void dilate_attn_kernel(
    const float* __restrict__ q, const float* __restrict__ k,
    const float* __restrict__ v, float* __restrict__ out) {
  const int tid   = blockIdx.x * 256 + threadIdx.x;
  const int lane  = threadIdx.x & 63;
  const int wav   = tid >> 6;              // 0..12287
  const int slice = lane >> 4;             // dd-octet owner
  const int wl    = lane & 15;             // window-pair within wave
  const int p     = (wav & 63) * 16 + wl;  // window-pair 0..1023
  const int bh    = wav >> 6;              // b*24 + hh
  const int hh    = bh % CH;
  const int b     = bh / CH;
  const int gg    = p * 2;                 // this thread: windows gg, gg+1

  // element offset of (row dd = hh*32+slice*8, j=0, col gg)
  const uint32_t inoff = (uint32_t)(b * CD + hh * HD + slice * 8) * (uint32_t)CN
                       + (uint32_t)gg;

  // ---- partial scores over this slice's 8 dd; float2 = {win gg, win gg+1}
  float2 s00 = {0.f, 0.f}, s01 = {0.f, 0.f}, s02 = {0.f, 0.f};
  float2 s10 = {0.f, 0.f}, s11 = {0.f, 0.f}, s12 = {0.f, 0.f};
  float2 s20 = {0.f, 0.f}, s21 = {0.f, 0.f}, s22 = {0.f, 0.f};
  #pragma unroll
  for (int d = 0; d < 8; ++d) {
    const uint32_t o = inoff + (uint32_t)d * CN;
    const float2 q0 = *reinterpret_cast<const float2*>(q + o);
    const float2 q1 = *reinterpret_cast<const float2*>(q + o + CG);
    const float2 q2 = *reinterpret_cast<const float2*>(q + o + 2 * CG);
    const float2 k0 = *reinterpret_cast<const float2*>(k + o);
    const float2 k1 = *reinterpret_cast<const float2*>(k + o + CG);
    const float2 k2 = *reinterpret_cast<const float2*>(k + o + 2 * CG);
    s00.x = fmaf(q0.x, k0.x, s00.x); s00.y = fmaf(q0.y, k0.y, s00.y);
    s01.x = fmaf(q0.x, k1.x, s01.x); s01.y = fmaf(q0.y, k1.y, s01.y);
    s02.x = fmaf(q0.x, k2.x, s02.x); s02.y = fmaf(q0.y, k2.y, s02.y);
    s10.x = fmaf(q1.x, k0.x, s10.x); s10.y = fmaf(q1.y, k0.y, s10.y);
    s11.x = fmaf(q1.x, k1.x, s11.x); s11.y = fmaf(q1.y, k1.y, s11.y);
    s12.x = fmaf(q1.x, k2.x, s12.x); s12.y = fmaf(q1.y, k2.y, s12.y);
    s20.x = fmaf(q2.x, k0.x, s20.x); s20.y = fmaf(q2.y, k0.y, s20.y);
    s21.x = fmaf(q2.x, k1.x, s21.x); s21.y = fmaf(q2.y, k1.y, s21.y);
    s22.x = fmaf(q2.x, k2.x, s22.x); s22.y = fmaf(q2.y, k2.y, s22.y);
  }

  // ---- issue v loads now; latency hides under shuffles + softmax
  float2 va[8], vb2[8], vc2[8];
  #pragma unroll
  for (int d = 0; d < 8; ++d) {
    const uint32_t o = inoff + (uint32_t)d * CN;
    va[d]  = *reinterpret_cast<const float2*>(v + o);
    vb2[d] = *reinterpret_cast<const float2*>(v + o + CG);
    vc2[d] = *reinterpret_cast<const float2*>(v + o + 2 * CG);
  }

  // ---- combine partial scores across the 4 slices (lane^16, lane^32)
  #pragma unroll
  for (int m = 16; m <= 32; m <<= 1) {
    s00.x += __shfl_xor(s00.x, m); s00.y += __shfl_xor(s00.y, m);
    s01.x += __shfl_xor(s01.x, m); s01.y += __shfl_xor(s01.y, m);
    s02.x += __shfl_xor(s02.x, m); s02.y += __shfl_xor(s02.y, m);
    s10.x += __shfl_xor(s10.x, m); s10.y += __shfl_xor(s10.y, m);
    s11.x += __shfl_xor(s11.x, m); s11.y += __shfl_xor(s11.y, m);
    s12.x += __shfl_xor(s12.x, m); s12.y += __shfl_xor(s12.y, m);
    s20.x += __shfl_xor(s20.x, m); s20.y += __shfl_xor(s20.y, m);
    s21.x += __shfl_xor(s21.x, m); s21.y += __shfl_xor(s21.y, m);
    s22.x += __shfl_xor(s22.x, m); s22.y += __shfl_xor(s22.y, m);
  }

  // ---- softmax over kj, in place, per (window-component, kq)
  const float scale = 0.17677669529663687f;  // 32^-0.5
  {
    float x0, x1, x2, m, e0, e1, e2, r;
    x0 = s00.x * scale; x1 = s01.x * scale; x2 = s02.x * scale;
    m = fmaxf(fmaxf(x0, x1), x2);
    e0 = __expf(x0 - m); e1 = __expf(x1 - m); e2 = __expf(x2 - m);
    r = 1.f / (e0 + e1 + e2); s00.x = e0 * r; s01.x = e1 * r; s02.x = e2 * r;
    x0 = s00.y * scale; x1 = s01.y * scale; x2 = s02.y * scale;
    m = fmaxf(fmaxf(x0, x1), x2);
    e0 = __expf(x0 - m); e1 = __expf(x1 - m); e2 = __expf(x2 - m);
    r = 1.f / (e0 + e1 + e2); s00.y = e0 * r; s01.y = e1 * r; s02.y = e2 * r;

    x0 = s10.x * scale; x1 = s11.x * scale; x2 = s12.x * scale;
    m = fmaxf(fmaxf(x0, x1), x2);
    e0 = __expf(x0 - m); e1 = __expf(x1 - m); e2 = __expf(x2 - m);
    r = 1.f / (e0 + e1 + e2); s10.x = e0 * r; s11.x = e1 * r; s12.x = e2 * r;
    x0 = s10.y * scale; x1 = s11.y * scale; x2 = s12.y * scale;
    m = fmaxf(fmaxf(x0, x1), x2);
    e0 = __expf(x0 - m); e1 = __expf(x1 - m); e2 = __expf(x2 - m);
    r = 1.f / (e0 + e1 + e2); s10.y = e0 * r; s11.y = e1 * r; s12.y = e2 * r;

    x0 = s20.x * scale; x1 = s21.x * scale; x2 = s22.x * scale;
    m = fmaxf(fmaxf(x0, x1), x2);
    e0 = __expf(x0 - m); e1 = __expf(x1 - m); e2 = __expf(x2 - m);
    r = 1.f / (e0 + e1 + e2); s20.x = e0 * r; s21.x = e1 * r; s22.x = e2 * r;
    x0 = s20.y * scale; x1 = s21.y * scale; x2 = s22.y * scale;
    m = fmaxf(fmaxf(x0, x1), x2);
    e0 = __expf(x0 - m); e1 = __expf(x1 - m); e2 = __expf(x2 - m);
    r = 1.f / (e0 + e1 + e2); s20.y = e0 * r; s21.y = e1 * r; s22.y = e2 * r;
  }

  // ---- PV from registers + stores: per window, per kq, one 32B pair of
  // float4 stores; window's 3 rows are 96 contiguous floats (amp-free, r8)
  const uint32_t ooff0 = (uint32_t)(b * CG + gg) * (uint32_t)OSTR
                       + (uint32_t)(hh * KS * HD + slice * 8);
  float o0, o1, o2, o3, o4, o5, o6, o7;

  // window gg (component .x)
  o0 = fmaf(s00.x, va[0].x, fmaf(s01.x, vb2[0].x, s02.x * vc2[0].x));
  o1 = fmaf(s00.x, va[1].x, fmaf(s01.x, vb2[1].x, s02.x * vc2[1].x));
  o2 = fmaf(s00.x, va[2].x, fmaf(s01.x, vb2[2].x, s02.x * vc2[2].x));
  o3 = fmaf(s00.x, va[3].x, fmaf(s01.x, vb2[3].x, s02.x * vc2[3].x));
  o4 = fmaf(s00.x, va[4].x, fmaf(s01.x, vb2[4].x, s02.x * vc2[4].x));
  o5 = fmaf(s00.x, va[5].x, fmaf(s01.x, vb2[5].x, s02.x * vc2[5].x));
  o6 = fmaf(s00.x, va[6].x, fmaf(s01.x, vb2[6].x, s02.x * vc2[6].x));
  o7 = fmaf(s00.x, va[7].x, fmaf(s01.x, vb2[7].x, s02.x * vc2[7].x));
  *reinterpret_cast<float4*>(out + ooff0 + 0 * HD)     = make_float4(o0, o1, o2, o3);
  *reinterpret_cast<float4*>(out + ooff0 + 0 * HD + 4) = make_float4(o4, o5, o6, o7);
  o0 = fmaf(s10.x, va[0].x, fmaf(s11.x, vb2[0].x, s12.x * vc2[0].x));
  o1 = fmaf(s10.x, va[1].x, fmaf(s11.x, vb2[1].x, s12.x * vc2[1].x));
  o2 = fmaf(s10.x, va[2].x, fmaf(s11.x, vb2[2].x, s12.x * vc2[2].x));
  o3 = fmaf(s10.x, va[3].x, fmaf(s11.x, vb2[3].x, s12.x * vc2[3].x));
  o4 = fmaf(s10.x, va[4].x, fmaf(s11.x, vb2[4].x, s12.x * vc2[4].x));
  o5 = fmaf(s10.x, va[5].x, fmaf(s11.x, vb2[5].x, s12.x * vc2[5].x));
  o6 = fmaf(s10.x, va[6].x, fmaf(s11.x, vb2[6].x, s12.x * vc2[6].x));
  o7 = fmaf(s10.x, va[7].x, fmaf(s11.x, vb2[7].x, s12.x * vc2[7].x));
  *reinterpret_cast<float4*>(out + ooff0 + 1 * HD)     = make_float4(o0, o1, o2, o3);
  *reinterpret_cast<float4*>(out + ooff0 + 1 * HD + 4) = make_float4(o4, o5, o6, o7);
  o0 = fmaf(s20.x, va[0].x, fmaf(s21.x, vb2[0].x, s22.x * vc2[0].x));
  o1 = fmaf(s20.x, va[1].x, fmaf(s21.x, vb2[1].x, s22.x * vc2[1].x));
  o2 = fmaf(s20.x, va[2].x, fmaf(s21.x, vb2[2].x, s22.x * vc2[2].x));
  o3 = fmaf(s20.x, va[3].x, fmaf(s21.x, vb2[3].x, s22.x * vc2[3].x));
  o4 = fmaf(s20.x, va[4].x, fmaf(s21.x, vb2[4].x, s22.x * vc2[4].x));
  o5 = fmaf(s20.x, va[5].x, fmaf(s21.x, vb2[5].x, s22.x * vc2[5].x));
  o6 = fmaf(s20.x, va[6].x, fmaf(s21.x, vb2[6].x, s22.x * vc2[6].x));
  o7 = fmaf(s20.x, va[7].x, fmaf(s21.x, vb2[7].x, s22.x * vc2[7].x));
  *reinterpret_cast<float4*>(out + ooff0 + 2 * HD)     = make_float4(o0, o1, o2, o3);
  *reinterpret_cast<float4*>(out + ooff0 + 2 * HD + 4) = make_float4(o4, o5, o6, o7);

  // window gg+1 (component .y)
  const uint32_t ooff1 = ooff0 + (uint32_t)OSTR;
  o0 = fmaf(s00.y, va[0].y, fmaf(s01.y, vb2[0].y, s02.y * vc2[0].y));
  o1 = fmaf(s00.y, va[1].y, fmaf(s01.y, vb2[1].y, s02.y * vc2[1].y));
  o2 = fmaf(s00.y, va[2].y, fmaf(s01.y, vb2[2].y, s02.y * vc2[2].y));
  o3 = fmaf(s00.y, va[3].y, fmaf(s01.y, vb2[3].y, s02.y * vc2[3].y));
  o4 = fmaf(s00.y, va[4].y, fmaf(s01.y, vb2[4].y, s02.y * vc2[4].y));
  o5 = fmaf(s00.y, va[5].y, fmaf(s01.y, vb2[5].y, s02.y * vc2[5].y));
  o6 = fmaf(s00.y, va[6].y, fmaf(s01.y, vb2[6].y, s02.y * vc2[6].y));
  o7 = fmaf(s00.y, va[7].y, fmaf(s01.y, vb2[7].y, s02.y * vc2[7].y));
  *reinterpret_cast<float4*>(out + ooff1 + 0 * HD)     = make_float4(o0, o1, o2, o3);
  *reinterpret_cast<float4*>(out + ooff1 + 0 * HD + 4) = make_float4(o4, o5, o6, o7);
  o0 = fmaf(s10.y, va[0].y, fmaf(s11.y, vb2[0].y, s12.y * vc2[0].y));
  o1 = fmaf(s10.y, va[1].y, fmaf(s11.y, vb2[1].y, s12.y * vc2[1].y));
  o2 = fmaf(s10.y, va[2].y, fmaf(s11.y, vb2[2].y, s12.y * vc2[2].y));
  o3 = fmaf(s10.y, va[3].y, fmaf(s11.y, vb2[3].y, s12.y * vc2[3].y));
  o4 = fmaf(s10.y, va[4].y, fmaf(s11.y, vb2[4].y, s12.y * vc2[4].y));
  o5 = fmaf(s10.y, va[5].y, fmaf(s11.y, vb2[5].y, s12.y * vc2[5].y));
  o6 = fmaf(s10.y, va[6].y, fmaf(s11.y, vb2[6].y, s12.y * vc2[6].y));
  o7 = fmaf(s10.y, va[7].y, fmaf(s11.y, vb2[7].y, s12.y * vc2[7].y));
  *reinterpret_cast<float4*>(out + ooff1 + 1 * HD)     = make_float4(o0, o1, o2, o3);
  *reinterpret_cast<float4*>(out + ooff1 + 1 * HD + 4) = make_float4(o4, o5, o6, o7);
  o0 = fmaf(s20.y, va[0].y, fmaf(s21.y, vb2[0].y, s22.y * vc2[0].y));
  o1 = fmaf(s20.y, va[1].y, fmaf(s21.y, vb2[1].y, s22.y * vc2[1].y));
  o2 = fmaf(s20.y, va[2].y, fmaf(s21.y, vb2[2].y, s22.y * vc2[2].y));
  o3 = fmaf(s20.y, va[3].y, fmaf(s21.y, vb2[3].y, s22.y * vc2[3].y));
  o4 = fmaf(s20.y, va[4].y, fmaf(s21.y, vb2[4].y, s22.y * vc2[4].y));
  o5 = fmaf(s20.y, va[5].y, fmaf(s21.y, vb2[5].y, s22.y * vc2[5].y));
  o6 = fmaf(s20.y, va[6].y, fmaf(s21.y, vb2[6].y, s22.y * vc2[6].y));
  o7 = fmaf(s20.y, va[7].y, fmaf(s21.y, vb2[7].y, s22.y * vc2[7].y));
  *reinterpret_cast<float4*>(out + ooff1 + 2 * HD)     = make_float4(o0, o1, o2, o3);
  *reinterpret_cast<float4*>(out + ooff1 + 2 * HD + 4) = make_float4(o4, o5, o6, o7);
}

extern "C" void kernel_launch(void* const* d_in, const int* in_sizes, int n_in,
                              void* d_out, int out_size, void* d_ws, size_t ws_size,
                              hipStream_t stream) {
  const float* q = (const float*)d_in[0];
  const float* k = (const float*)d_in[1];
  const float* v = (const float*)d_in[2];
  float* out = (float*)d_out;

  const int total = CB * CH * (CG / 2) * 4;  // 786432 threads, 4 per window-pair
  const int blocks = total / 256;            // 3072 blocks = 12288 waves
  dilate_attn_kernel<<<blocks, 256, 0, stream>>>(q, k, v, out);
}